// Round 15
// baseline (59.094 us; speedup 1.0000x reference)
//
#include <hip/hip_runtime.h>
#include <cstdint>
#include <cstddef>

constexpr int D = 64;
constexpr int TWO_D = 128;
constexpr int NB = 4;      // b's per block in agg (software-pipelined)

typedef __attribute__((ext_vector_type(8))) short bf16x8;
typedef __attribute__((ext_vector_type(4))) float f32x4;
typedef __attribute__((ext_vector_type(4))) unsigned short u16x4;

static __device__ __forceinline__ short f2bf(float x) {
    unsigned u = __builtin_bit_cast(unsigned, x);
    u += 0x7fffu + ((u >> 16) & 1u);          // round-to-nearest-even
    return (short)(u >> 16);
}
static __device__ __forceinline__ float bf2f(unsigned short h) {
    return __builtin_bit_cast(float, ((unsigned)h) << 16);
}
static __device__ __forceinline__ bf16x8 cvt8(const float* p) {
    const float4 a = *(const float4*)p;
    const float4 c = *(const float4*)(p + 4);
    bf16x8 f;
    f[0] = f2bf(a.x); f[1] = f2bf(a.y); f[2] = f2bf(a.z); f[3] = f2bf(a.w);
    f[4] = f2bf(c.x); f[5] = f2bf(c.y); f[6] = f2bf(c.z); f[7] = f2bf(c.w);
    return f;
}
static __device__ __forceinline__ bf16x8 pack2(const float4& a, const float4& c) {
    bf16x8 f;
    f[0] = f2bf(a.x); f[1] = f2bf(a.y); f[2] = f2bf(a.z); f[3] = f2bf(a.w);
    f[4] = f2bf(c.x); f[5] = f2bf(c.y); f[6] = f2bf(c.z); f[7] = f2bf(c.w);
    return f;
}

// ---------------------------------------------------------------------------
// Kernel 1: S table (tiny GEMM) + W1F/W2F fragment pack (unchanged from R14).
// ---------------------------------------------------------------------------
__global__ __launch_bounds__(256) void proj_s(
    const float* __restrict__ u_to_e, const int* __restrict__ nodes,
    const float* __restrict__ att1_w, const float* __restrict__ att1_b,
    const float* __restrict__ att2_w,
    float* __restrict__ S, unsigned short* __restrict__ W1F,
    unsigned short* __restrict__ W2F,
    int Bn, int nSB)
{
    const int tid = threadIdx.x;

    if ((int)blockIdx.x == nSB) {                    // pack block
        if (tid < 64) {
            const int plg = tid >> 4, plc = tid & 15;
#pragma unroll
            for (int tc = 0; tc < 4; ++tc)
#pragma unroll
                for (int ks = 0; ks < 2; ++ks) {
                    const bf16x8 f1 = cvt8(
                        att1_w + (tc * 16 + plc) * TWO_D + ks * 32 + plg * 8);
                    *(bf16x8*)(W1F + ((size_t)(tc * 2 + ks) * 64 + tid) * 8) = f1;
                    const bf16x8 f2 = cvt8(
                        att2_w + (tc * 16 + plc) * D + ks * 32 + plg * 8);
                    *(bf16x8*)(W2F + ((size_t)(tc * 2 + ks) * 64 + tid) * 8) = f2;
                }
        }
        return;
    }

    constexpr int ST = 68;
    __shared__ float xs[64 * ST];
    __shared__ float ws[64 * ST];

    const int base = (int)blockIdx.x * 64;

#pragma unroll
    for (int it = 0; it < 4; ++it) {
        const int flat = it * 256 + tid;
        const int dd = flat >> 4, f4 = flat & 15;
        const float4 w = *(const float4*)(att1_w + dd * TWO_D + D + f4 * 4);
        ws[(f4 * 4 + 0) * ST + dd] = w.x;
        ws[(f4 * 4 + 1) * ST + dd] = w.y;
        ws[(f4 * 4 + 2) * ST + dd] = w.z;
        ws[(f4 * 4 + 3) * ST + dd] = w.w;
    }
#pragma unroll
    for (int it = 0; it < 4; ++it) {
        const int flat = it * 256 + tid;
        const int r = flat >> 4, f4 = flat & 15;
        int gr = base + r;
        if (gr >= Bn) gr = Bn - 1;
        const int row = nodes[gr];
        const float4 x = *(const float4*)(u_to_e + (size_t)row * D + f4 * 4);
        xs[(f4 * 4 + 0) * ST + r] = x.x;
        xs[(f4 * 4 + 1) * ST + r] = x.y;
        xs[(f4 * 4 + 2) * ST + r] = x.z;
        xs[(f4 * 4 + 3) * ST + r] = x.w;
    }
    __syncthreads();

    const int d0 = (tid & 15) * 4;
    const int r0 = (tid >> 4) * 4;
    float acc[4][4];
#pragma unroll
    for (int i = 0; i < 4; ++i)
#pragma unroll
        for (int j = 0; j < 4; ++j) acc[i][j] = 0.f;

#pragma unroll 8
    for (int f = 0; f < D; ++f) {
        const float4 w = *(const float4*)&ws[f * ST + d0];
        const float4 x = *(const float4*)&xs[f * ST + r0];
        const float wv[4] = {w.x, w.y, w.z, w.w};
        const float xv[4] = {x.x, x.y, x.z, x.w};
#pragma unroll
        for (int ri = 0; ri < 4; ++ri)
#pragma unroll
            for (int di = 0; di < 4; ++di)
                acc[ri][di] += xv[ri] * wv[di];
    }

    float bv[4];
#pragma unroll
    for (int di = 0; di < 4; ++di) bv[di] = att1_b[d0 + di];
#pragma unroll
    for (int ri = 0; ri < 4; ++ri) {
        const int gr = base + r0 + ri;
        if (gr < Bn) {
            float4 o = {acc[ri][0] + bv[0], acc[ri][1] + bv[1],
                        acc[ri][2] + bv[2], acc[ri][3] + bv[3]};
            *(float4*)(S + (size_t)gr * D + d0) = o;
        }
    }
}

// ---------------------------------------------------------------------------
// Kernel 2 (fused + software-pipelined): block = NB consecutive b's.
// Iteration i+1's history/v_to_e loads are issued mid-iteration-i (raw fp32,
// bf16 conversion deferred to consume time) so gather latency hides under the
// current iteration's MFMA/softmax/barrier tail. Per-b structure = R14.
// ---------------------------------------------------------------------------
__global__ __launch_bounds__(256) void agg_fused(
    const int* __restrict__ history, const int* __restrict__ degrees,
    const float* __restrict__ v_to_e,
    const float* __restrict__ att2_b, const float* __restrict__ att3_w,
    const float* __restrict__ S,
    const unsigned short* __restrict__ W1F,
    const unsigned short* __restrict__ W2F,
    float* __restrict__ out, int Bn, int K)
{
    __shared__ unsigned short hldsb[4][16 * 72];   // per-wave bf16 h1 tiles
    __shared__ float red[4][64];
    __shared__ float mxs[4];
    __shared__ float sms[4];

    const int wslot = threadIdx.x >> 6;
    const int l     = threadIdx.x & 63;
    const int lg    = l >> 4;
    const int lc    = l & 15;

    int kpos = wslot * 16 + lc;
    if (kpos > K - 1) kpos = K - 1;                // clamped history column

    const int b0 = (int)blockIdx.x * NB;

    // ---- pipeline preamble: loads for iteration 0 ----
    int    deg  = 0, vrow = 0;
    float4 vr4[4];
    float4 bvr[4];                                  // raw v-row slices
    if (b0 < Bn) {
        deg  = degrees[b0];
        vrow = history[(size_t)b0 * K + kpos];
        if (wslot * 16 < deg) {
#pragma unroll
            for (int jj = 0; jj < 4; ++jj) {
                const int row = __shfl(vrow, jj * 4 + lg);
                vr4[jj] = *(const float4*)(v_to_e + (size_t)row * D + lc * 4);
            }
            const float* vp = v_to_e + (size_t)vrow * D;
            bvr[0] = *(const float4*)(vp + lg * 8);
            bvr[1] = *(const float4*)(vp + lg * 8 + 4);
            bvr[2] = *(const float4*)(vp + 32 + lg * 8);
            bvr[3] = *(const float4*)(vp + 32 + lg * 8 + 4);
        }
    }

    for (int i = 0; i < NB; ++i) {
        const int  bcur  = b0 + i;
        const bool valid = (bcur < Bn);             // block-uniform
        const bool live  = valid && (wslot * 16 < deg);
        const bool act   = valid && (wslot * 16 + lc < deg);

        // ---- issue next-iteration control loads early ----
        const int  bnext  = bcur + 1;
        const bool validN = (i + 1 < NB) && (bnext < Bn);
        int degN = 0, vrowN = 0;
        if (validN) {
            degN  = degrees[bnext];
            vrowN = history[(size_t)bnext * K + kpos];
        }

        float m_w = -1e30f, ex = 0.f;
        float4 acc4 = {0.f, 0.f, 0.f, 0.f};

        bf16x8 af0, af1;
        if (live) {
            // ---- H1T = W1n x v^T; +S, relu, bf16 -> per-wave LDS tile ----
            const bf16x8 bv0 = pack2(bvr[0], bvr[1]);
            const bf16x8 bv1 = pack2(bvr[2], bvr[3]);
            unsigned short* hrow = &hldsb[wslot][0];
#pragma unroll
            for (int tc = 0; tc < 4; ++tc) {
                f32x4 hacc = (f32x4)0.f;
                const bf16x8 w10 = *(const bf16x8*)(
                    W1F + ((size_t)(tc * 2 + 0) * 64 + l) * 8);
                hacc = __builtin_amdgcn_mfma_f32_16x16x32_bf16(w10, bv0, hacc, 0, 0, 0);
                const bf16x8 w11 = *(const bf16x8*)(
                    W1F + ((size_t)(tc * 2 + 1) * 64 + l) * 8);
                hacc = __builtin_amdgcn_mfma_f32_16x16x32_bf16(w11, bv1, hacc, 0, 0, 0);
                const float4 sv = *(const float4*)(S + (size_t)bcur * D + tc * 16 + lg * 4);
                u16x4 hb;
                hb[0] = (unsigned short)f2bf(fmaxf(hacc[0] + sv.x, 0.f));
                hb[1] = (unsigned short)f2bf(fmaxf(hacc[1] + sv.y, 0.f));
                hb[2] = (unsigned short)f2bf(fmaxf(hacc[2] + sv.z, 0.f));
                hb[3] = (unsigned short)f2bf(fmaxf(hacc[3] + sv.w, 0.f));
                *(u16x4*)&hrow[lc * 72 + tc * 16 + lg * 4] = hb;
            }
            // same-wave LDS read in af layout (no barrier needed)
            af0 = *(const bf16x8*)&hrow[lc * 72 + lg * 8];
            af1 = *(const bf16x8*)&hrow[lc * 72 + 32 + lg * 8];
        }

        // ---- issue next-iteration data loads (hide under tail of iter i) --
        float4 vr4n[4];
        float4 bvrn[4];
        const bool liveN = validN && (wslot * 16 < degN);
        if (liveN) {
#pragma unroll
            for (int jj = 0; jj < 4; ++jj) {
                const int row = __shfl(vrowN, jj * 4 + lg);
                vr4n[jj] = *(const float4*)(v_to_e + (size_t)row * D + lc * 4);
            }
            const float* vp = v_to_e + (size_t)vrowN * D;
            bvrn[0] = *(const float4*)(vp + lg * 8);
            bvrn[1] = *(const float4*)(vp + lg * 8 + 4);
            bvrn[2] = *(const float4*)(vp + 32 + lg * 8);
            bvrn[3] = *(const float4*)(vp + 32 + lg * 8 + 4);
        }

        if (live) {
            // ---- per-tc W2 MFMA + fused epilogue ----
            float part = 0.f;
#pragma unroll
            for (int tc = 0; tc < 4; ++tc) {
                f32x4 acc = (f32x4)0.f;
                const bf16x8 w0 = *(const bf16x8*)(
                    W2F + ((size_t)(tc * 2 + 0) * 64 + l) * 8);
                acc = __builtin_amdgcn_mfma_f32_16x16x32_bf16(w0, af0, acc, 0, 0, 0);
                const bf16x8 w1 = *(const bf16x8*)(
                    W2F + ((size_t)(tc * 2 + 1) * 64 + l) * 8);
                acc = __builtin_amdgcn_mfma_f32_16x16x32_bf16(w1, af1, acc, 0, 0, 0);
                const float4 b2v = *(const float4*)(att2_b + tc * 16 + lg * 4);
                const float4 w3v = *(const float4*)(att3_w + tc * 16 + lg * 4);
                part += fmaxf(acc[0] + b2v.x, 0.f) * w3v.x;
                part += fmaxf(acc[1] + b2v.y, 0.f) * w3v.y;
                part += fmaxf(acc[2] + b2v.z, 0.f) * w3v.z;
                part += fmaxf(acc[3] + b2v.w, 0.f) * w3v.w;
            }
            part += __shfl_xor(part, 16);
            part += __shfl_xor(part, 32);
            const float logit = act ? part : -1e30f;

            // ---- per-wave softmax partials (flash style) ----
            m_w = logit;
#pragma unroll
            for (int off = 1; off < 16; off <<= 1)
                m_w = fmaxf(m_w, __shfl_xor(m_w, off));
            ex = act ? __expf(logit - m_w) : 0.f;
            float s_w = ex;
#pragma unroll
            for (int off = 1; off < 16; off <<= 1)
                s_w += __shfl_xor(s_w, off);
            if (l == 0) { mxs[wslot] = m_w; sms[wslot] = s_w; }

            // ---- value FMA with unnormalized weights (before barrier) ----
#pragma unroll
            for (int jj = 0; jj < 4; ++jj) {
                const float a = __shfl(ex, jj * 4 + lg);
                acc4.x += a * vr4[jj].x;
                acc4.y += a * vr4[jj].y;
                acc4.z += a * vr4[jj].z;
                acc4.w += a * vr4[jj].w;
            }
            acc4.x += __shfl_xor(acc4.x, 16); acc4.x += __shfl_xor(acc4.x, 32);
            acc4.y += __shfl_xor(acc4.y, 16); acc4.y += __shfl_xor(acc4.y, 32);
            acc4.z += __shfl_xor(acc4.z, 16); acc4.z += __shfl_xor(acc4.z, 32);
            acc4.w += __shfl_xor(acc4.w, 16); acc4.w += __shfl_xor(acc4.w, 32);
        } else if (valid) {
            if (l == 0) { mxs[wslot] = -1e30f; sms[wslot] = 0.f; }
        }

        if (valid) {
            __syncthreads();
            const float m = fmaxf(fmaxf(mxs[0], mxs[1]), fmaxf(mxs[2], mxs[3]));
            const float tot = sms[0] * __expf(mxs[0] - m) + sms[1] * __expf(mxs[1] - m)
                            + sms[2] * __expf(mxs[2] - m) + sms[3] * __expf(mxs[3] - m);
            const float scale = live ? __expf(m_w - m) / tot : 0.f;
            const float comp = (lg == 0) ? acc4.x : (lg == 1) ? acc4.y
                             : (lg == 2) ? acc4.z : acc4.w;
            red[wslot][lc * 4 + lg] = comp * scale;
            __syncthreads();
            if (wslot == 0)
                out[(size_t)bcur * D + l] =
                    (red[0][l] + red[1][l]) + (red[2][l] + red[3][l]);
        }

        // ---- rotate pipeline registers ----
        deg  = degN;
        vrow = vrowN;
#pragma unroll
        for (int jj = 0; jj < 4; ++jj) { vr4[jj] = vr4n[jj]; bvr[jj] = bvrn[jj]; }
    }
}

// ---------------------------------------------------------------------------
// Fallback (no workspace): fused fp32 kernel, one wave per b.
// ---------------------------------------------------------------------------
__global__ __launch_bounds__(256) void agg_fallback(
    const int* __restrict__ nodes, const int* __restrict__ history,
    const int* __restrict__ degrees,
    const float* __restrict__ u_to_e, const float* __restrict__ v_to_e,
    const float* __restrict__ att1_w, const float* __restrict__ att1_b,
    const float* __restrict__ att2_w, const float* __restrict__ att2_b,
    const float* __restrict__ att3_w, const float* __restrict__ att3_b,
    float* __restrict__ out, int Bn, int K)
{
    const int b    = (int)((blockIdx.x * blockDim.x + threadIdx.x) >> 6);
    const int lane = threadIdx.x & 63;
    if (b >= Bn) return;

    const int  deg    = degrees[b];
    const bool active = (lane < deg);
    const int  v      = history[(size_t)b * K + ((lane < K) ? lane : 0)];

    float h1[D];
    float vr[D];
    const float4* v4 = (const float4*)(v_to_e + (size_t)v * D);
#pragma unroll
    for (int i = 0; i < D / 4; ++i) {
        float4 t = v4[i];
        vr[4 * i + 0] = t.x; vr[4 * i + 1] = t.y;
        vr[4 * i + 2] = t.z; vr[4 * i + 3] = t.w;
    }
    const float* urow = u_to_e + (size_t)nodes[b] * D;
#pragma unroll
    for (int d = 0; d < D; ++d) {
        const float* w1 = att1_w + d * TWO_D;
        float a0 = att1_b[d], a1 = 0.f, a2 = 0.f, a3 = 0.f;
#pragma unroll
        for (int f = 0; f < D; f += 4) {
            a0 += vr[f + 0] * w1[f + 0];
            a1 += vr[f + 1] * w1[f + 1];
            a2 += vr[f + 2] * w1[f + 2];
            a3 += vr[f + 3] * w1[f + 3];
            a0 += urow[f + 0] * w1[D + f + 0];
            a1 += urow[f + 1] * w1[D + f + 1];
            a2 += urow[f + 2] * w1[D + f + 2];
            a3 += urow[f + 3] * w1[D + f + 3];
        }
        h1[d] = fmaxf((a0 + a1) + (a2 + a3), 0.f);
    }

    float logit = att3_b[0];
#pragma unroll 4
    for (int e = 0; e < D; ++e) {
        const float* w2r = att2_w + e * D;
        float a0 = 0.f, a1 = 0.f, a2 = 0.f, a3 = 0.f;
#pragma unroll
        for (int dd = 0; dd < D; dd += 4) {
            a0 += h1[dd + 0] * w2r[dd + 0];
            a1 += h1[dd + 1] * w2r[dd + 1];
            a2 += h1[dd + 2] * w2r[dd + 2];
            a3 += h1[dd + 3] * w2r[dd + 3];
        }
        float h2 = (a0 + a1) + (a2 + a3) + att2_b[e];
        logit += fmaxf(h2, 0.f) * att3_w[e];
    }

    float ml = active ? logit : -1e30f;
#pragma unroll
    for (int off = 32; off > 0; off >>= 1) ml = fmaxf(ml, __shfl_xor(ml, off));
    const float ex = active ? __expf(logit - ml) : 0.f;
    float smv = ex;
#pragma unroll
    for (int off = 32; off > 0; off >>= 1) smv += __shfl_xor(smv, off);
    const float att = ex / smv;

    float acc = 0.f;
    for (int kk = 0; kk < deg; ++kk) {
        const float a  = __shfl(att, kk);
        const int   vk = __shfl(v, kk);
        acc += a * v_to_e[(size_t)vk * D + lane];
    }
    out[(size_t)b * D + lane] = acc;
}

// ---------------------------------------------------------------------------
extern "C" void kernel_launch(void* const* d_in, const int* in_sizes, int n_in,
                              void* d_out, int out_size, void* d_ws, size_t ws_size,
                              hipStream_t stream)
{
    const int*   nodes   = (const int*)d_in[0];
    const int*   history = (const int*)d_in[1];
    const int*   degrees = (const int*)d_in[2];
    const float* u_to_e  = (const float*)d_in[3];
    const float* v_to_e  = (const float*)d_in[4];
    const float* att1_w  = (const float*)d_in[5];
    const float* att1_b  = (const float*)d_in[6];
    const float* att2_w  = (const float*)d_in[7];
    const float* att2_b  = (const float*)d_in[8];
    const float* att3_w  = (const float*)d_in[9];
    const float* att3_b  = (const float*)d_in[10];
    float*       out     = (float*)d_out;

    const int Bn = in_sizes[0];
    const int K  = in_sizes[1] / Bn;

    // ws: S (fp32 Bn*D) | W1F (8 KB) | W2F (8 KB)
    const size_t s_bytes   = (size_t)Bn * D * sizeof(float);
    const size_t wf_bytes  = (size_t)8 * 64 * 8 * sizeof(unsigned short);
    const size_t need = s_bytes + 2 * wf_bytes;

    if (ws_size >= need) {
        char* p = (char*)d_ws;
        float*          S   = (float*)p;            p += s_bytes;
        unsigned short* W1F = (unsigned short*)p;   p += wf_bytes;
        unsigned short* W2F = (unsigned short*)p;
        const int nSB = (Bn + 63) / 64;
        proj_s<<<nSB + 1, 256, 0, stream>>>(
            u_to_e, nodes, att1_w, att1_b, att2_w, S, W1F, W2F, Bn, nSB);
        agg_fused<<<(Bn + NB - 1) / NB, 256, 0, stream>>>(
            history, degrees, v_to_e, att2_b, att3_w,
            S, W1F, W2F, out, Bn, K);
    } else {
        const int agg_blocks = (Bn * 64 + 255) / 256;
        agg_fallback<<<agg_blocks, 256, 0, stream>>>(
            nodes, history, degrees, u_to_e, v_to_e,
            att1_w, att1_b, att2_w, att2_b, att3_w, att3_b,
            out, Bn, K);
    }
}

// Round 16
// 49.433 us; speedup vs baseline: 1.1954x; 1.1954x over previous
//
#include <hip/hip_runtime.h>
#include <cstdint>
#include <cstddef>

constexpr int D = 64;
constexpr int TWO_D = 128;

typedef __attribute__((ext_vector_type(8))) short bf16x8;
typedef __attribute__((ext_vector_type(4))) float f32x4;
typedef __attribute__((ext_vector_type(4))) unsigned short u16x4;

static __device__ __forceinline__ short f2bf(float x) {
    unsigned u = __builtin_bit_cast(unsigned, x);
    u += 0x7fffu + ((u >> 16) & 1u);          // round-to-nearest-even
    return (short)(u >> 16);
}
static __device__ __forceinline__ bf16x8 cvt8(const float* p) {
    const float4 a = *(const float4*)p;
    const float4 c = *(const float4*)(p + 4);
    bf16x8 f;
    f[0] = f2bf(a.x); f[1] = f2bf(a.y); f[2] = f2bf(a.z); f[3] = f2bf(a.w);
    f[4] = f2bf(c.x); f[5] = f2bf(c.y); f[6] = f2bf(c.z); f[7] = f2bf(c.w);
    return f;
}
static __device__ __forceinline__ bf16x8 pack2(const float4& a, const float4& c) {
    bf16x8 f;
    f[0] = f2bf(a.x); f[1] = f2bf(a.y); f[2] = f2bf(a.z); f[3] = f2bf(a.w);
    f[4] = f2bf(c.x); f[5] = f2bf(c.y); f[6] = f2bf(c.z); f[7] = f2bf(c.w);
    return f;
}

// ---------------------------------------------------------------------------
// Kernel 1: S table (tiny GEMM) + W1F/W2F fragment pack (unchanged from R14).
// ---------------------------------------------------------------------------
__global__ __launch_bounds__(256) void proj_s(
    const float* __restrict__ u_to_e, const int* __restrict__ nodes,
    const float* __restrict__ att1_w, const float* __restrict__ att1_b,
    const float* __restrict__ att2_w,
    float* __restrict__ S, unsigned short* __restrict__ W1F,
    unsigned short* __restrict__ W2F,
    int Bn, int nSB)
{
    const int tid = threadIdx.x;

    if ((int)blockIdx.x == nSB) {                    // pack block
        if (tid < 64) {
            const int plg = tid >> 4, plc = tid & 15;
#pragma unroll
            for (int tc = 0; tc < 4; ++tc)
#pragma unroll
                for (int ks = 0; ks < 2; ++ks) {
                    const bf16x8 f1 = cvt8(
                        att1_w + (tc * 16 + plc) * TWO_D + ks * 32 + plg * 8);
                    *(bf16x8*)(W1F + ((size_t)(tc * 2 + ks) * 64 + tid) * 8) = f1;
                    const bf16x8 f2 = cvt8(
                        att2_w + (tc * 16 + plc) * D + ks * 32 + plg * 8);
                    *(bf16x8*)(W2F + ((size_t)(tc * 2 + ks) * 64 + tid) * 8) = f2;
                }
        }
        return;
    }

    constexpr int ST = 68;
    __shared__ float xs[64 * ST];
    __shared__ float ws[64 * ST];

    const int base = (int)blockIdx.x * 64;

#pragma unroll
    for (int it = 0; it < 4; ++it) {
        const int flat = it * 256 + tid;
        const int dd = flat >> 4, f4 = flat & 15;
        const float4 w = *(const float4*)(att1_w + dd * TWO_D + D + f4 * 4);
        ws[(f4 * 4 + 0) * ST + dd] = w.x;
        ws[(f4 * 4 + 1) * ST + dd] = w.y;
        ws[(f4 * 4 + 2) * ST + dd] = w.z;
        ws[(f4 * 4 + 3) * ST + dd] = w.w;
    }
#pragma unroll
    for (int it = 0; it < 4; ++it) {
        const int flat = it * 256 + tid;
        const int r = flat >> 4, f4 = flat & 15;
        int gr = base + r;
        if (gr >= Bn) gr = Bn - 1;
        const int row = nodes[gr];
        const float4 x = *(const float4*)(u_to_e + (size_t)row * D + f4 * 4);
        xs[(f4 * 4 + 0) * ST + r] = x.x;
        xs[(f4 * 4 + 1) * ST + r] = x.y;
        xs[(f4 * 4 + 2) * ST + r] = x.z;
        xs[(f4 * 4 + 3) * ST + r] = x.w;
    }
    __syncthreads();

    const int d0 = (tid & 15) * 4;
    const int r0 = (tid >> 4) * 4;
    float acc[4][4];
#pragma unroll
    for (int i = 0; i < 4; ++i)
#pragma unroll
        for (int j = 0; j < 4; ++j) acc[i][j] = 0.f;

#pragma unroll 8
    for (int f = 0; f < D; ++f) {
        const float4 w = *(const float4*)&ws[f * ST + d0];
        const float4 x = *(const float4*)&xs[f * ST + r0];
        const float wv[4] = {w.x, w.y, w.z, w.w};
        const float xv[4] = {x.x, x.y, x.z, x.w};
#pragma unroll
        for (int ri = 0; ri < 4; ++ri)
#pragma unroll
            for (int di = 0; di < 4; ++di)
                acc[ri][di] += xv[ri] * wv[di];
    }

    float bv[4];
#pragma unroll
    for (int di = 0; di < 4; ++di) bv[di] = att1_b[d0 + di];
#pragma unroll
    for (int ri = 0; ri < 4; ++ri) {
        const int gr = base + r0 + ri;
        if (gr < Bn) {
            float4 o = {acc[ri][0] + bv[0], acc[ri][1] + bv[1],
                        acc[ri][2] + bv[2], acc[ri][3] + bv[3]};
            *(float4*)(S + (size_t)gr * D + d0) = o;
        }
    }
}

// ---------------------------------------------------------------------------
// Kernel 2 (one wave per b, ZERO barriers): wave processes its b's 4 k-tiles
// sequentially with ONLINE softmax (running m,s + value-acc rescale).
// All cross-lane ops are in-wave shuffles; the h1 LDS tile is same-wave
// write->read (no barrier). Tile t+1's v_to_e loads are issued at the top of
// tile t's body and stay in flight across 16 MFMAs + softmax — no barrier
// ever drains them (the R15 failure mode eliminated structurally).
// ---------------------------------------------------------------------------
__global__ __launch_bounds__(256) void agg_wave(
    const int* __restrict__ history, const int* __restrict__ degrees,
    const float* __restrict__ v_to_e,
    const float* __restrict__ att2_b, const float* __restrict__ att3_w,
    const float* __restrict__ S,
    const unsigned short* __restrict__ W1F,
    const unsigned short* __restrict__ W2F,
    float* __restrict__ out, int Bn, int K)
{
    __shared__ unsigned short hldsb[4][16 * 72];   // per-wave bf16 h1 tile

    const int wslot = threadIdx.x >> 6;
    const int b     = (int)blockIdx.x * 4 + wslot;
    if (b >= Bn) return;
    const int l  = threadIdx.x & 63;
    const int lg = l >> 4;
    const int lc = l & 15;
    const int deg = degrees[b];                    // wave-uniform

    // ---- all neighbor row ids upfront (addresses for every tile) ----
    int vrow[4];
#pragma unroll
    for (int t = 0; t < 4; ++t) {
        int kp = t * 16 + lc;
        if (kp > K - 1) kp = K - 1;
        vrow[t] = history[(size_t)b * K + kp];
    }

    // ---- S row + epilogue constants hoisted (loop-invariant) ----
    float4 sv[4], b2v[4], w3v[4];
#pragma unroll
    for (int tc = 0; tc < 4; ++tc) {
        sv[tc]  = *(const float4*)(S + (size_t)b * D + tc * 16 + lg * 4);
        b2v[tc] = *(const float4*)(att2_b + tc * 16 + lg * 4);
        w3v[tc] = *(const float4*)(att3_w + tc * 16 + lg * 4);
    }

    unsigned short* hrow = &hldsb[wslot][0];

    // ---- pipeline buffers (parity-indexed, fully unrolled -> static) ----
    float4 bvr[2][4];     // v row slices for h1 B-frag  (tile parity)
    float4 vr4[2][4];     // wide value rows             (tile parity)

    // preamble: tile 0 data loads
    {
        const float* vp = v_to_e + (size_t)vrow[0] * D;
        bvr[0][0] = *(const float4*)(vp + lg * 8);
        bvr[0][1] = *(const float4*)(vp + lg * 8 + 4);
        bvr[0][2] = *(const float4*)(vp + 32 + lg * 8);
        bvr[0][3] = *(const float4*)(vp + 32 + lg * 8 + 4);
#pragma unroll
        for (int jj = 0; jj < 4; ++jj) {
            const int row = __shfl(vrow[0], jj * 4 + lg);
            vr4[0][jj] = *(const float4*)(v_to_e + (size_t)row * D + lc * 4);
        }
    }

    float m_run = -1e30f, s_run = 0.f;
    float4 acc4 = {0.f, 0.f, 0.f, 0.f};

#pragma unroll
    for (int t = 0; t < 4; ++t) {
        if (t * 16 < deg) {                        // wave-uniform tile skip
            const int cur = t & 1, nxt = cur ^ 1;

            // ---- issue tile t+1 loads FIRST (hide under this tile) ----
            if (t + 1 < 4 && (t + 1) * 16 < deg) {
                const float* vp = v_to_e + (size_t)vrow[t + 1] * D;
                bvr[nxt][0] = *(const float4*)(vp + lg * 8);
                bvr[nxt][1] = *(const float4*)(vp + lg * 8 + 4);
                bvr[nxt][2] = *(const float4*)(vp + 32 + lg * 8);
                bvr[nxt][3] = *(const float4*)(vp + 32 + lg * 8 + 4);
#pragma unroll
                for (int jj = 0; jj < 4; ++jj) {
                    const int row = __shfl(vrow[t + 1], jj * 4 + lg);
                    vr4[nxt][jj] = *(const float4*)(v_to_e + (size_t)row * D + lc * 4);
                }
            }

            // ---- h1 for this tile's 16 neighbors via W1 MFMA ----
            const bf16x8 bv0 = pack2(bvr[cur][0], bvr[cur][1]);
            const bf16x8 bv1 = pack2(bvr[cur][2], bvr[cur][3]);
#pragma unroll
            for (int tc = 0; tc < 4; ++tc) {
                f32x4 hacc = (f32x4)0.f;
                const bf16x8 w10 = *(const bf16x8*)(
                    W1F + ((size_t)(tc * 2 + 0) * 64 + l) * 8);
                hacc = __builtin_amdgcn_mfma_f32_16x16x32_bf16(w10, bv0, hacc, 0, 0, 0);
                const bf16x8 w11 = *(const bf16x8*)(
                    W1F + ((size_t)(tc * 2 + 1) * 64 + l) * 8);
                hacc = __builtin_amdgcn_mfma_f32_16x16x32_bf16(w11, bv1, hacc, 0, 0, 0);
                u16x4 hb;
                hb[0] = (unsigned short)f2bf(fmaxf(hacc[0] + sv[tc].x, 0.f));
                hb[1] = (unsigned short)f2bf(fmaxf(hacc[1] + sv[tc].y, 0.f));
                hb[2] = (unsigned short)f2bf(fmaxf(hacc[2] + sv[tc].z, 0.f));
                hb[3] = (unsigned short)f2bf(fmaxf(hacc[3] + sv[tc].w, 0.f));
                *(u16x4*)&hrow[lc * 72 + tc * 16 + lg * 4] = hb;
            }
            // same-wave LDS read in af layout (no barrier needed)
            const bf16x8 af0 = *(const bf16x8*)&hrow[lc * 72 + lg * 8];
            const bf16x8 af1 = *(const bf16x8*)&hrow[lc * 72 + 32 + lg * 8];

            // ---- W2 MFMA + fused epilogue -> logit[k=lc] ----
            float part = 0.f;
#pragma unroll
            for (int tc = 0; tc < 4; ++tc) {
                f32x4 acc = (f32x4)0.f;
                const bf16x8 w0 = *(const bf16x8*)(
                    W2F + ((size_t)(tc * 2 + 0) * 64 + l) * 8);
                acc = __builtin_amdgcn_mfma_f32_16x16x32_bf16(w0, af0, acc, 0, 0, 0);
                const bf16x8 w1 = *(const bf16x8*)(
                    W2F + ((size_t)(tc * 2 + 1) * 64 + l) * 8);
                acc = __builtin_amdgcn_mfma_f32_16x16x32_bf16(w1, af1, acc, 0, 0, 0);
                part += fmaxf(acc[0] + b2v[tc].x, 0.f) * w3v[tc].x;
                part += fmaxf(acc[1] + b2v[tc].y, 0.f) * w3v[tc].y;
                part += fmaxf(acc[2] + b2v[tc].z, 0.f) * w3v[tc].z;
                part += fmaxf(acc[3] + b2v[tc].w, 0.f) * w3v[tc].w;
            }
            part += __shfl_xor(part, 16);
            part += __shfl_xor(part, 32);
            const bool actk = (t * 16 + lc < deg);
            const float logit = actk ? part : -1e30f;

            // ---- online softmax update (in-wave only) ----
            float mt = logit;
#pragma unroll
            for (int off = 1; off < 16; off <<= 1)
                mt = fmaxf(mt, __shfl_xor(mt, off));
            const float m_new = fmaxf(m_run, mt);
            const float scale_old = __expf(m_run - m_new);   // 0 on first tile
            const float ex = actk ? __expf(logit - m_new) : 0.f;
            float st = ex;
#pragma unroll
            for (int off = 1; off < 16; off <<= 1)
                st += __shfl_xor(st, off);
            s_run = s_run * scale_old + st;
            m_run = m_new;
            acc4.x *= scale_old; acc4.y *= scale_old;
            acc4.z *= scale_old; acc4.w *= scale_old;

            // ---- value FMA for this tile (unnormalized ex weights) ----
#pragma unroll
            for (int jj = 0; jj < 4; ++jj) {
                const float a = __shfl(ex, jj * 4 + lg);
                acc4.x += a * vr4[cur][jj].x;
                acc4.y += a * vr4[cur][jj].y;
                acc4.z += a * vr4[cur][jj].z;
                acc4.w += a * vr4[cur][jj].w;
            }
        }
    }

    // ---- final: reduce over the 4 k-subgroups (lg axis), normalize ----
    acc4.x += __shfl_xor(acc4.x, 16); acc4.x += __shfl_xor(acc4.x, 32);
    acc4.y += __shfl_xor(acc4.y, 16); acc4.y += __shfl_xor(acc4.y, 32);
    acc4.z += __shfl_xor(acc4.z, 16); acc4.z += __shfl_xor(acc4.z, 32);
    acc4.w += __shfl_xor(acc4.w, 16); acc4.w += __shfl_xor(acc4.w, 32);

    const float comp = (lg == 0) ? acc4.x : (lg == 1) ? acc4.y
                     : (lg == 2) ? acc4.z : acc4.w;
    out[(size_t)b * D + lc * 4 + lg] = comp / s_run;
}

// ---------------------------------------------------------------------------
// Fallback (no workspace): fused fp32 kernel, one wave per b.
// ---------------------------------------------------------------------------
__global__ __launch_bounds__(256) void agg_fallback(
    const int* __restrict__ nodes, const int* __restrict__ history,
    const int* __restrict__ degrees,
    const float* __restrict__ u_to_e, const float* __restrict__ v_to_e,
    const float* __restrict__ att1_w, const float* __restrict__ att1_b,
    const float* __restrict__ att2_w, const float* __restrict__ att2_b,
    const float* __restrict__ att3_w, const float* __restrict__ att3_b,
    float* __restrict__ out, int Bn, int K)
{
    const int b    = (int)((blockIdx.x * blockDim.x + threadIdx.x) >> 6);
    const int lane = threadIdx.x & 63;
    if (b >= Bn) return;

    const int  deg    = degrees[b];
    const bool active = (lane < deg);
    const int  v      = history[(size_t)b * K + ((lane < K) ? lane : 0)];

    float h1[D];
    float vr[D];
    const float4* v4 = (const float4*)(v_to_e + (size_t)v * D);
#pragma unroll
    for (int i = 0; i < D / 4; ++i) {
        float4 t = v4[i];
        vr[4 * i + 0] = t.x; vr[4 * i + 1] = t.y;
        vr[4 * i + 2] = t.z; vr[4 * i + 3] = t.w;
    }
    const float* urow = u_to_e + (size_t)nodes[b] * D;
#pragma unroll
    for (int d = 0; d < D; ++d) {
        const float* w1 = att1_w + d * TWO_D;
        float a0 = att1_b[d], a1 = 0.f, a2 = 0.f, a3 = 0.f;
#pragma unroll
        for (int f = 0; f < D; f += 4) {
            a0 += vr[f + 0] * w1[f + 0];
            a1 += vr[f + 1] * w1[f + 1];
            a2 += vr[f + 2] * w1[f + 2];
            a3 += vr[f + 3] * w1[f + 3];
            a0 += urow[f + 0] * w1[D + f + 0];
            a1 += urow[f + 1] * w1[D + f + 1];
            a2 += urow[f + 2] * w1[D + f + 2];
            a3 += urow[f + 3] * w1[D + f + 3];
        }
        h1[d] = fmaxf((a0 + a1) + (a2 + a3), 0.f);
    }

    float logit = att3_b[0];
#pragma unroll 4
    for (int e = 0; e < D; ++e) {
        const float* w2r = att2_w + e * D;
        float a0 = 0.f, a1 = 0.f, a2 = 0.f, a3 = 0.f;
#pragma unroll
        for (int dd = 0; dd < D; dd += 4) {
            a0 += h1[dd + 0] * w2r[dd + 0];
            a1 += h1[dd + 1] * w2r[dd + 1];
            a2 += h1[dd + 2] * w2r[dd + 2];
            a3 += h1[dd + 3] * w2r[dd + 3];
        }
        float h2 = (a0 + a1) + (a2 + a3) + att2_b[e];
        logit += fmaxf(h2, 0.f) * att3_w[e];
    }

    float ml = active ? logit : -1e30f;
#pragma unroll
    for (int off = 32; off > 0; off >>= 1) ml = fmaxf(ml, __shfl_xor(ml, off));
    const float ex = active ? __expf(logit - ml) : 0.f;
    float smv = ex;
#pragma unroll
    for (int off = 32; off > 0; off >>= 1) smv += __shfl_xor(smv, off);
    const float att = ex / smv;

    float acc = 0.f;
    for (int kk = 0; kk < deg; ++kk) {
        const float a  = __shfl(att, kk);
        const int   vk = __shfl(v, kk);
        acc += a * v_to_e[(size_t)vk * D + lane];
    }
    out[(size_t)b * D + lane] = acc;
}

// ---------------------------------------------------------------------------
extern "C" void kernel_launch(void* const* d_in, const int* in_sizes, int n_in,
                              void* d_out, int out_size, void* d_ws, size_t ws_size,
                              hipStream_t stream)
{
    const int*   nodes   = (const int*)d_in[0];
    const int*   history = (const int*)d_in[1];
    const int*   degrees = (const int*)d_in[2];
    const float* u_to_e  = (const float*)d_in[3];
    const float* v_to_e  = (const float*)d_in[4];
    const float* att1_w  = (const float*)d_in[5];
    const float* att1_b  = (const float*)d_in[6];
    const float* att2_w  = (const float*)d_in[7];
    const float* att2_b  = (const float*)d_in[8];
    const float* att3_w  = (const float*)d_in[9];
    const float* att3_b  = (const float*)d_in[10];
    float*       out     = (float*)d_out;

    const int Bn = in_sizes[0];
    const int K  = in_sizes[1] / Bn;

    // ws: S (fp32 Bn*D) | W1F (8 KB) | W2F (8 KB)
    const size_t s_bytes   = (size_t)Bn * D * sizeof(float);
    const size_t wf_bytes  = (size_t)8 * 64 * 8 * sizeof(unsigned short);
    const size_t need = s_bytes + 2 * wf_bytes;

    if (ws_size >= need) {
        char* p = (char*)d_ws;
        float*          S   = (float*)p;            p += s_bytes;
        unsigned short* W1F = (unsigned short*)p;   p += wf_bytes;
        unsigned short* W2F = (unsigned short*)p;
        const int nSB = (Bn + 63) / 64;
        proj_s<<<nSB + 1, 256, 0, stream>>>(
            u_to_e, nodes, att1_w, att1_b, att2_w, S, W1F, W2F, Bn, nSB);
        agg_wave<<<(Bn + 3) / 4, 256, 0, stream>>>(
            history, degrees, v_to_e, att2_b, att3_w,
            S, W1F, W2F, out, Bn, K);
    } else {
        const int agg_blocks = (Bn * 64 + 255) / 256;
        agg_fallback<<<agg_blocks, 256, 0, stream>>>(
            nodes, history, degrees, u_to_e, v_to_e,
            att1_w, att1_b, att2_w, att2_b, att3_w, att3_b,
            out, Bn, K);
    }
}

// Round 17
// 43.701 us; speedup vs baseline: 1.3522x; 1.1312x over previous
//
#include <hip/hip_runtime.h>
#include <cstdint>
#include <cstddef>

constexpr int D = 64;
constexpr int TWO_D = 128;

typedef __attribute__((ext_vector_type(8))) short bf16x8;
typedef __attribute__((ext_vector_type(4))) float f32x4;
typedef __attribute__((ext_vector_type(4))) unsigned short u16x4;

static __device__ __forceinline__ short f2bf(float x) {
    unsigned u = __builtin_bit_cast(unsigned, x);
    u += 0x7fffu + ((u >> 16) & 1u);          // round-to-nearest-even
    return (short)(u >> 16);
}
static __device__ __forceinline__ bf16x8 cvt8(const float* p) {
    const float4 a = *(const float4*)p;
    const float4 c = *(const float4*)(p + 4);
    bf16x8 f;
    f[0] = f2bf(a.x); f[1] = f2bf(a.y); f[2] = f2bf(a.z); f[3] = f2bf(a.w);
    f[4] = f2bf(c.x); f[5] = f2bf(c.y); f[6] = f2bf(c.z); f[7] = f2bf(c.w);
    return f;
}
static __device__ __forceinline__ bf16x8 pack2(const float4& a, const float4& c) {
    bf16x8 f;
    f[0] = f2bf(a.x); f[1] = f2bf(a.y); f[2] = f2bf(a.z); f[3] = f2bf(a.w);
    f[4] = f2bf(c.x); f[5] = f2bf(c.y); f[6] = f2bf(c.z); f[7] = f2bf(c.w);
    return f;
}

// ---------------------------------------------------------------------------
// Kernel 1: S table (tiny GEMM) + W1F/W2F fragment pack (unchanged from R14).
// ---------------------------------------------------------------------------
__global__ __launch_bounds__(256) void proj_s(
    const float* __restrict__ u_to_e, const int* __restrict__ nodes,
    const float* __restrict__ att1_w, const float* __restrict__ att1_b,
    const float* __restrict__ att2_w,
    float* __restrict__ S, unsigned short* __restrict__ W1F,
    unsigned short* __restrict__ W2F,
    int Bn, int nSB)
{
    const int tid = threadIdx.x;

    if ((int)blockIdx.x == nSB) {                    // pack block
        if (tid < 64) {
            const int plg = tid >> 4, plc = tid & 15;
#pragma unroll
            for (int tc = 0; tc < 4; ++tc)
#pragma unroll
                for (int ks = 0; ks < 2; ++ks) {
                    const bf16x8 f1 = cvt8(
                        att1_w + (tc * 16 + plc) * TWO_D + ks * 32 + plg * 8);
                    *(bf16x8*)(W1F + ((size_t)(tc * 2 + ks) * 64 + tid) * 8) = f1;
                    const bf16x8 f2 = cvt8(
                        att2_w + (tc * 16 + plc) * D + ks * 32 + plg * 8);
                    *(bf16x8*)(W2F + ((size_t)(tc * 2 + ks) * 64 + tid) * 8) = f2;
                }
        }
        return;
    }

    constexpr int ST = 68;
    __shared__ float xs[64 * ST];
    __shared__ float ws[64 * ST];

    const int base = (int)blockIdx.x * 64;

#pragma unroll
    for (int it = 0; it < 4; ++it) {
        const int flat = it * 256 + tid;
        const int dd = flat >> 4, f4 = flat & 15;
        const float4 w = *(const float4*)(att1_w + dd * TWO_D + D + f4 * 4);
        ws[(f4 * 4 + 0) * ST + dd] = w.x;
        ws[(f4 * 4 + 1) * ST + dd] = w.y;
        ws[(f4 * 4 + 2) * ST + dd] = w.z;
        ws[(f4 * 4 + 3) * ST + dd] = w.w;
    }
#pragma unroll
    for (int it = 0; it < 4; ++it) {
        const int flat = it * 256 + tid;
        const int r = flat >> 4, f4 = flat & 15;
        int gr = base + r;
        if (gr >= Bn) gr = Bn - 1;
        const int row = nodes[gr];
        const float4 x = *(const float4*)(u_to_e + (size_t)row * D + f4 * 4);
        xs[(f4 * 4 + 0) * ST + r] = x.x;
        xs[(f4 * 4 + 1) * ST + r] = x.y;
        xs[(f4 * 4 + 2) * ST + r] = x.z;
        xs[(f4 * 4 + 3) * ST + r] = x.w;
    }
    __syncthreads();

    const int d0 = (tid & 15) * 4;
    const int r0 = (tid >> 4) * 4;
    float acc[4][4];
#pragma unroll
    for (int i = 0; i < 4; ++i)
#pragma unroll
        for (int j = 0; j < 4; ++j) acc[i][j] = 0.f;

#pragma unroll 8
    for (int f = 0; f < D; ++f) {
        const float4 w = *(const float4*)&ws[f * ST + d0];
        const float4 x = *(const float4*)&xs[f * ST + r0];
        const float wv[4] = {w.x, w.y, w.z, w.w};
        const float xv[4] = {x.x, x.y, x.z, x.w};
#pragma unroll
        for (int ri = 0; ri < 4; ++ri)
#pragma unroll
            for (int di = 0; di < 4; ++di)
                acc[ri][di] += xv[ri] * wv[di];
    }

    float bv[4];
#pragma unroll
    for (int di = 0; di < 4; ++di) bv[di] = att1_b[d0 + di];
#pragma unroll
    for (int ri = 0; ri < 4; ++ri) {
        const int gr = base + r0 + ri;
        if (gr < Bn) {
            float4 o = {acc[ri][0] + bv[0], acc[ri][1] + bv[1],
                        acc[ri][2] + bv[2], acc[ri][3] + bv[3]};
            *(float4*)(S + (size_t)gr * D + d0) = o;
        }
    }
}

// ---------------------------------------------------------------------------
// Kernel 2 (R14 structure + ONE barrier + setprio around MFMA clusters):
// block = one b, wave wslot = k-tile. h1 on the fly (W1 MFMA from gathered v
// rows, +S relu, per-wave LDS roundtrip), W2 MFMA -> logits, per-wave flash
// (m_w, s_w), value FMA with UNNORMALIZED weights, then a SINGLE barrier:
// red[w] holds raw od; wave 0 applies exp(m_w-m)/tot per slot in the final sum.
// ---------------------------------------------------------------------------
__global__ __launch_bounds__(256) void agg_fused(
    const int* __restrict__ history, const int* __restrict__ degrees,
    const float* __restrict__ v_to_e,
    const float* __restrict__ att2_b, const float* __restrict__ att3_w,
    const float* __restrict__ S,
    const unsigned short* __restrict__ W1F,
    const unsigned short* __restrict__ W2F,
    float* __restrict__ out, int Bn, int K)
{
    __shared__ unsigned short hldsb[4][16 * 72];   // per-wave bf16 h1 tiles
    __shared__ float red[4][64];
    __shared__ float mxs[4];
    __shared__ float sms[4];

    const int b     = (int)blockIdx.x;
    const int wslot = threadIdx.x >> 6;
    const int l     = threadIdx.x & 63;
    const int lg    = l >> 4;
    const int lc    = l & 15;
    const int deg   = degrees[b];                 // uniform
    const bool live = (wslot * 16 < deg);         // wave-uniform
    const bool act  = (wslot * 16 + lc < deg);

    int kk = wslot * 16 + lc;
    if (kk > K - 1) kk = K - 1;
    const int vrow = history[(size_t)b * K + kk];   // row id for k_local = lc

    // ---- value prefetch FIRST: 4 wide fp32 loads (4 rows each, R10) ----
    float4 vr4[4];
    if (live) {
#pragma unroll
        for (int jj = 0; jj < 4; ++jj) {
            const int row = __shfl(vrow, jj * 4 + lg);
            vr4[jj] = *(const float4*)(v_to_e + (size_t)row * D + lc * 4);
        }
    }

    float m_w = -1e30f, s_w = 0.f;
    float4 acc4 = {0.f, 0.f, 0.f, 0.f};
    if (live) {
        // ---- B-frag of v for the H1T MFMA (same rows as value path -> L1) --
        const float* vp = v_to_e + (size_t)vrow * D;
        const bf16x8 bv0 = cvt8(vp + lg * 8);          // feat 0..31 slice
        const bf16x8 bv1 = cvt8(vp + 32 + lg * 8);     // feat 32..63 slice

        // ---- per-tc: H1T chunk = W1n x v^T; +S, relu, bf16 -> LDS ----
        unsigned short* hrow = &hldsb[wslot][0];
        __builtin_amdgcn_s_setprio(1);
#pragma unroll
        for (int tc = 0; tc < 4; ++tc) {
            f32x4 hacc = (f32x4)0.f;
            const bf16x8 w10 = *(const bf16x8*)(
                W1F + ((size_t)(tc * 2 + 0) * 64 + l) * 8);
            hacc = __builtin_amdgcn_mfma_f32_16x16x32_bf16(w10, bv0, hacc, 0, 0, 0);
            const bf16x8 w11 = *(const bf16x8*)(
                W1F + ((size_t)(tc * 2 + 1) * 64 + l) * 8);
            hacc = __builtin_amdgcn_mfma_f32_16x16x32_bf16(w11, bv1, hacc, 0, 0, 0);
            // lane holds H1T[d = tc*16 + lg*4 + r][neighbor lc]
            const float4 sv = *(const float4*)(S + (size_t)b * D + tc * 16 + lg * 4);
            u16x4 hb;
            hb[0] = (unsigned short)f2bf(fmaxf(hacc[0] + sv.x, 0.f));
            hb[1] = (unsigned short)f2bf(fmaxf(hacc[1] + sv.y, 0.f));
            hb[2] = (unsigned short)f2bf(fmaxf(hacc[2] + sv.z, 0.f));
            hb[3] = (unsigned short)f2bf(fmaxf(hacc[3] + sv.w, 0.f));
            *(u16x4*)&hrow[lc * 72 + tc * 16 + lg * 4] = hb;
        }
        __builtin_amdgcn_s_setprio(0);

        // ---- same-wave LDS read in af layout (R4-proven, no barrier) ----
        const bf16x8 af0 = *(const bf16x8*)&hrow[lc * 72 + lg * 8];
        const bf16x8 af1 = *(const bf16x8*)&hrow[lc * 72 + 32 + lg * 8];

        // ---- per-tc W2 MFMA + fused epilogue (single live accumulator) ----
        float part = 0.f;
        __builtin_amdgcn_s_setprio(1);
#pragma unroll
        for (int tc = 0; tc < 4; ++tc) {
            f32x4 acc = (f32x4)0.f;
            const bf16x8 w0 = *(const bf16x8*)(
                W2F + ((size_t)(tc * 2 + 0) * 64 + l) * 8);
            acc = __builtin_amdgcn_mfma_f32_16x16x32_bf16(w0, af0, acc, 0, 0, 0);
            const bf16x8 w1 = *(const bf16x8*)(
                W2F + ((size_t)(tc * 2 + 1) * 64 + l) * 8);
            acc = __builtin_amdgcn_mfma_f32_16x16x32_bf16(w1, af1, acc, 0, 0, 0);
            const float4 b2v = *(const float4*)(att2_b + tc * 16 + lg * 4);
            const float4 w3v = *(const float4*)(att3_w + tc * 16 + lg * 4);
            part += fmaxf(acc[0] + b2v.x, 0.f) * w3v.x;
            part += fmaxf(acc[1] + b2v.y, 0.f) * w3v.y;
            part += fmaxf(acc[2] + b2v.z, 0.f) * w3v.z;
            part += fmaxf(acc[3] + b2v.w, 0.f) * w3v.w;
        }
        __builtin_amdgcn_s_setprio(0);
        part += __shfl_xor(part, 16);
        part += __shfl_xor(part, 32);
        const float logit = act ? part : -1e30f;

        // ---- per-wave softmax partials (flash style) ----
        m_w = logit;
#pragma unroll
        for (int off = 1; off < 16; off <<= 1)
            m_w = fmaxf(m_w, __shfl_xor(m_w, off));
        const float ex = act ? __expf(logit - m_w) : 0.f;
        s_w = ex;
#pragma unroll
        for (int off = 1; off < 16; off <<= 1)
            s_w += __shfl_xor(s_w, off);

        // ---- value FMA with UNNORMALIZED weights (before barrier) ----
#pragma unroll
        for (int jj = 0; jj < 4; ++jj) {
            const float a = __shfl(ex, jj * 4 + lg);
            acc4.x += a * vr4[jj].x;
            acc4.y += a * vr4[jj].y;
            acc4.z += a * vr4[jj].z;
            acc4.w += a * vr4[jj].w;
        }
        acc4.x += __shfl_xor(acc4.x, 16); acc4.x += __shfl_xor(acc4.x, 32);
        acc4.y += __shfl_xor(acc4.y, 16); acc4.y += __shfl_xor(acc4.y, 32);
        acc4.z += __shfl_xor(acc4.z, 16); acc4.z += __shfl_xor(acc4.z, 32);
        acc4.w += __shfl_xor(acc4.w, 16); acc4.w += __shfl_xor(acc4.w, 32);
    }

    // ---- SINGLE barrier: publish raw od + (m_w, s_w) ----
    if (l == 0) { mxs[wslot] = m_w; sms[wslot] = s_w; }
    const float comp = (lg == 0) ? acc4.x : (lg == 1) ? acc4.y
                     : (lg == 2) ? acc4.z : acc4.w;
    red[wslot][lc * 4 + lg] = comp;                  // unnormalized
    __syncthreads();

    if (wslot == 0) {
        const float m = fmaxf(fmaxf(mxs[0], mxs[1]), fmaxf(mxs[2], mxs[3]));
        const float e0 = __expf(mxs[0] - m), e1 = __expf(mxs[1] - m);
        const float e2 = __expf(mxs[2] - m), e3 = __expf(mxs[3] - m);
        const float tot = sms[0] * e0 + sms[1] * e1 + sms[2] * e2 + sms[3] * e3;
        out[(size_t)b * D + l] =
            (red[0][l] * e0 + red[1][l] * e1 + red[2][l] * e2 + red[3][l] * e3)
            / tot;
    }
}

// ---------------------------------------------------------------------------
// Fallback (no workspace): fused fp32 kernel, one wave per b.
// ---------------------------------------------------------------------------
__global__ __launch_bounds__(256) void agg_fallback(
    const int* __restrict__ nodes, const int* __restrict__ history,
    const int* __restrict__ degrees,
    const float* __restrict__ u_to_e, const float* __restrict__ v_to_e,
    const float* __restrict__ att1_w, const float* __restrict__ att1_b,
    const float* __restrict__ att2_w, const float* __restrict__ att2_b,
    const float* __restrict__ att3_w, const float* __restrict__ att3_b,
    float* __restrict__ out, int Bn, int K)
{
    const int b    = (int)((blockIdx.x * blockDim.x + threadIdx.x) >> 6);
    const int lane = threadIdx.x & 63;
    if (b >= Bn) return;

    const int  deg    = degrees[b];
    const bool active = (lane < deg);
    const int  v      = history[(size_t)b * K + ((lane < K) ? lane : 0)];

    float h1[D];
    float vr[D];
    const float4* v4 = (const float4*)(v_to_e + (size_t)v * D);
#pragma unroll
    for (int i = 0; i < D / 4; ++i) {
        float4 t = v4[i];
        vr[4 * i + 0] = t.x; vr[4 * i + 1] = t.y;
        vr[4 * i + 2] = t.z; vr[4 * i + 3] = t.w;
    }
    const float* urow = u_to_e + (size_t)nodes[b] * D;
#pragma unroll
    for (int d = 0; d < D; ++d) {
        const float* w1 = att1_w + d * TWO_D;
        float a0 = att1_b[d], a1 = 0.f, a2 = 0.f, a3 = 0.f;
#pragma unroll
        for (int f = 0; f < D; f += 4) {
            a0 += vr[f + 0] * w1[f + 0];
            a1 += vr[f + 1] * w1[f + 1];
            a2 += vr[f + 2] * w1[f + 2];
            a3 += vr[f + 3] * w1[f + 3];
            a0 += urow[f + 0] * w1[D + f + 0];
            a1 += urow[f + 1] * w1[D + f + 1];
            a2 += urow[f + 2] * w1[D + f + 2];
            a3 += urow[f + 3] * w1[D + f + 3];
        }
        h1[d] = fmaxf((a0 + a1) + (a2 + a3), 0.f);
    }

    float logit = att3_b[0];
#pragma unroll 4
    for (int e = 0; e < D; ++e) {
        const float* w2r = att2_w + e * D;
        float a0 = 0.f, a1 = 0.f, a2 = 0.f, a3 = 0.f;
#pragma unroll
        for (int dd = 0; dd < D; dd += 4) {
            a0 += h1[dd + 0] * w2r[dd + 0];
            a1 += h1[dd + 1] * w2r[dd + 1];
            a2 += h1[dd + 2] * w2r[dd + 2];
            a3 += h1[dd + 3] * w2r[dd + 3];
        }
        float h2 = (a0 + a1) + (a2 + a3) + att2_b[e];
        logit += fmaxf(h2, 0.f) * att3_w[e];
    }

    float ml = active ? logit : -1e30f;
#pragma unroll
    for (int off = 32; off > 0; off >>= 1) ml = fmaxf(ml, __shfl_xor(ml, off));
    const float ex = active ? __expf(logit - ml) : 0.f;
    float smv = ex;
#pragma unroll
    for (int off = 32; off > 0; off >>= 1) smv += __shfl_xor(smv, off);
    const float att = ex / smv;

    float acc = 0.f;
    for (int kk = 0; kk < deg; ++kk) {
        const float a  = __shfl(att, kk);
        const int   vk = __shfl(v, kk);
        acc += a * v_to_e[(size_t)vk * D + lane];
    }
    out[(size_t)b * D + lane] = acc;
}

// ---------------------------------------------------------------------------
extern "C" void kernel_launch(void* const* d_in, const int* in_sizes, int n_in,
                              void* d_out, int out_size, void* d_ws, size_t ws_size,
                              hipStream_t stream)
{
    const int*   nodes   = (const int*)d_in[0];
    const int*   history = (const int*)d_in[1];
    const int*   degrees = (const int*)d_in[2];
    const float* u_to_e  = (const float*)d_in[3];
    const float* v_to_e  = (const float*)d_in[4];
    const float* att1_w  = (const float*)d_in[5];
    const float* att1_b  = (const float*)d_in[6];
    const float* att2_w  = (const float*)d_in[7];
    const float* att2_b  = (const float*)d_in[8];
    const float* att3_w  = (const float*)d_in[9];
    const float* att3_b  = (const float*)d_in[10];
    float*       out     = (float*)d_out;

    const int Bn = in_sizes[0];
    const int K  = in_sizes[1] / Bn;

    // ws: S (fp32 Bn*D) | W1F (8 KB) | W2F (8 KB)
    const size_t s_bytes   = (size_t)Bn * D * sizeof(float);
    const size_t wf_bytes  = (size_t)8 * 64 * 8 * sizeof(unsigned short);
    const size_t need = s_bytes + 2 * wf_bytes;

    if (ws_size >= need) {
        char* p = (char*)d_ws;
        float*          S   = (float*)p;            p += s_bytes;
        unsigned short* W1F = (unsigned short*)p;   p += wf_bytes;
        unsigned short* W2F = (unsigned short*)p;
        const int nSB = (Bn + 63) / 64;
        proj_s<<<nSB + 1, 256, 0, stream>>>(
            u_to_e, nodes, att1_w, att1_b, att2_w, S, W1F, W2F, Bn, nSB);
        agg_fused<<<Bn, 256, 0, stream>>>(
            history, degrees, v_to_e, att2_b, att3_w,
            S, W1F, W2F, out, Bn, K);
    } else {
        const int agg_blocks = (Bn * 64 + 255) / 256;
        agg_fallback<<<agg_blocks, 256, 0, stream>>>(
            nodes, history, degrees, u_to_e, v_to_e,
            att1_w, att1_b, att2_w, att2_b, att3_w, att3_b,
            out, Bn, K);
    }
}